// Round 18
// baseline (526.277 us; speedup 1.0000x reference)
//
#include <hip/hip_runtime.h>
#include <math.h>

// Problem constants (fixed by the reference)
constexpr int kN0 = 400000, kN1 = 100000, kN2 = 20000;
constexpr int kE1 = 1000000, kE2 = 200000;
constexpr int kIN = 128, kHID = 256, kOUT = 47;
constexpr float kEPS = 1e-5f, kNEG = 0.2f;

#define DEV static __device__ __forceinline__

typedef __attribute__((ext_vector_type(8))) short short8;
typedef __attribute__((ext_vector_type(4))) float f32x4;

DEV float b2f(unsigned short u) { return __uint_as_float(((unsigned)u) << 16); }
DEV unsigned short f2bf(float f) {
    unsigned u = __float_as_uint(f);
    unsigned r = (u + 0x7fffu + ((u >> 16) & 1u)) >> 16;   // RNE
    return (unsigned short)r;
}
DEV float lrelu(float v) { return v > 0.f ? v : kNEG * v; }

DEV void gload_lds16(const void* g, void* l) {
    __builtin_amdgcn_global_load_lds(
        (const __attribute__((address_space(1))) void*)g,
        (__attribute__((address_space(3))) void*)l, 16, 0, 0);
}

DEV unsigned pack2(float a, float b) {
    return (unsigned)f2bf(a) | ((unsigned)f2bf(b) << 16);
}
DEV unsigned long long pack4(float a, float b, float c, float d) {
    return (unsigned long long)pack2(a, b) | ((unsigned long long)pack2(c, d) << 32);
}

// ---- merged init: zero zreg + weight precompute (v1t, v2t, Wcat1t, Wcat2t, Wm1t) ----
constexpr int kNZreg = 1536 + 2 * kN1 + 2 * kN2;   // 241536
__global__ void prep_all(const float* __restrict__ W1, const float* __restrict__ as1,
                         const float* __restrict__ ad1,
                         const float* __restrict__ W2, const float* __restrict__ as2,
                         const float* __restrict__ ad2,
                         const float* __restrict__ Wsk1, const float* __restrict__ Wsk2,
                         const float* __restrict__ Wm1,
                         float* __restrict__ zreg,
                         unsigned short* __restrict__ v1t, unsigned short* __restrict__ v2t,
                         unsigned short* __restrict__ Wcat1t,
                         unsigned short* __restrict__ Wcat2t,
                         unsigned short* __restrict__ Wm1t) {
    int i = blockIdx.x * blockDim.x + threadIdx.x;
    if (i < kNZreg) { zreg[i] = 0.f; return; }
    i -= kNZreg;
    if (i < 2048) {                       // v1t[16][128]
        int j = i >> 7, k = i & 127;
        float s = 0.f;
        if (j < 8) {
            int h = j & 3;
            const float* a = (j >= 4) ? ad1 : as1;
            for (int c = 0; c < 64; ++c) s += W1[(size_t)k * 256 + h * 64 + c] * a[h * 64 + c];
        }
        v1t[i] = f2bf(s);
        return;
    }
    i -= 2048;
    if (i < 4096) {                       // v2t[16][256]
        int j = i >> 8, k = i & 255;
        float s = 0.f;
        if (j < 8) {
            int h = j & 3;
            const float* a = (j >= 4) ? ad2 : as2;
            for (int c = 0; c < 64; ++c) s += W2[(size_t)k * 256 + h * 64 + c] * a[h * 64 + c];
        }
        v2t[i] = f2bf(s);
        return;
    }
    i -= 4096;
    if (i < 163840) {                     // Wcat1t[256][640]
        int n = i / 640, k = i % 640;
        float v;
        if (k < 512) { int h = k >> 7, kin = k & 127; v = ((n >> 6) == h) ? W1[(size_t)kin * 256 + n] : 0.f; }
        else v = Wsk1[(size_t)(k - 512) * 256 + n];
        Wcat1t[i] = f2bf(v);
        return;
    }
    i -= 163840;
    if (i < 327680) {                     // Wcat2t[256][1280]
        int n = i / 1280, k = i % 1280;
        float v;
        if (k < 1024) { int h = k >> 8, kin = k & 255; v = ((n >> 6) == h) ? W2[(size_t)kin * 256 + n] : 0.f; }
        else v = Wsk2[(size_t)(k - 1024) * 256 + n];
        Wcat2t[i] = f2bf(v);
        return;
    }
    i -= 327680;
    if (i < 65536) {                      // Wm1t[256][256]
        int n = i >> 8, k = i & 255;
        Wm1t[i] = f2bf(Wm1[(size_t)k * 256 + n]);
    }
}

// ---- dst histogram, both layers (standalone: atomics don't pollute conv's L2 streams) ----
__global__ void hist_both(const int* __restrict__ dst1, int* __restrict__ cnt1,
                          const int* __restrict__ dst2, int* __restrict__ cnt2) {
    int e = blockIdx.x * blockDim.x + threadIdx.x;
    if (e < kE1) atomicAdd(&cnt1[dst1[e]], 1);
    else { e -= kE1; if (e < kE2) atomicAdd(&cnt2[dst2[e]], 1); }
}

// ---- x->bf16 (linear R/W) + layer-1 dots via LDS-redistributed MFMA (pure streaming) ----
// Block = 4 waves = 64 rows. Phase 1: linear coalesced read/convert/write + swizzled LDS
// stage. Phase 2: ds_read MFMA fragments (same XOR involution) + dots.
__global__ __launch_bounds__(256) void conv_als(const float* __restrict__ x,
                                                const unsigned short* __restrict__ v1t,
                                                unsigned short* __restrict__ xb,
                                                float* __restrict__ als,
                                                float* __restrict__ ald) {
    __shared__ unsigned short lds[64 * 128];   // 16 KB
    const int tid = threadIdx.x;
    const int base = (int)blockIdx.x * 64;     // first row of this block

    // ---- phase 1: linear read x, convert, linear write xb, swizzled LDS stage ----
    #pragma unroll
    for (int j = 0; j < 4; ++j) {
        int u = j * 256 + tid;                 // ushort8 slot index, 0..1023
        int row = u >> 4, g = u & 15;
        size_t fo = (size_t)(base + row) * 128 + g * 8;
        float4 xa = *reinterpret_cast<const float4*>(&x[fo]);
        float4 xc = *reinterpret_cast<const float4*>(&x[fo + 4]);
        short8 af;
        af[0] = (short)f2bf(xa.x); af[1] = (short)f2bf(xa.y);
        af[2] = (short)f2bf(xa.z); af[3] = (short)f2bf(xa.w);
        af[4] = (short)f2bf(xc.x); af[5] = (short)f2bf(xc.y);
        af[6] = (short)f2bf(xc.z); af[7] = (short)f2bf(xc.w);
        *reinterpret_cast<short8*>(&xb[fo]) = af;                       // linear, coalesced
        int gs = g ^ (row & 7);                                         // bank-spread involution
        *reinterpret_cast<short8*>(&lds[row * 128 + gs * 8]) = af;
    }
    __syncthreads();

    // ---- phase 2: MFMA dots from LDS fragments ----
    int wid = tid >> 6, lane = tid & 63;
    int l15 = lane & 15, l4 = lane >> 4;
    short8 bfr[4];
    #pragma unroll
    for (int ks = 0; ks < 4; ++ks)
        bfr[ks] = *reinterpret_cast<const short8*>(&v1t[l15 * 128 + ks * 32 + l4 * 8]);

    int rl = wid * 16 + l15;                   // local row for A fragment
    f32x4 acc = (f32x4){0.f, 0.f, 0.f, 0.f};
    #pragma unroll
    for (int ks = 0; ks < 4; ++ks) {
        int g0 = ks * 4 + l4;
        int gs = g0 ^ (rl & 7);
        short8 af = *reinterpret_cast<const short8*>(&lds[rl * 128 + gs * 8]);
        acc = __builtin_amdgcn_mfma_f32_16x16x32_bf16(af, bfr[ks], acc, 0, 0, 0);
    }
    if (l15 < 8) {
        int tilebase = base + wid * 16;
        #pragma unroll
        for (int i = 0; i < 4; ++i) {
            int node = tilebase + l4 * 4 + i;
            if (l15 < 4) als[(size_t)node * 4 + l15] = acc[i];
            else if (node < kN1) ald[(size_t)node * 4 + (l15 - 4)] = acc[i];
        }
    }
}

// ---- fused BN(ELU) bf16->bf16 (+ optional layer-2 attention dots via MFMA) ----
template <bool AL>
__global__ __launch_bounds__(256) void bn_mfma(const unsigned short* __restrict__ X,
                                               const float* __restrict__ stats,
                                               const float* __restrict__ gamma,
                                               const float* __restrict__ beta,
                                               unsigned short* __restrict__ outb,
                                               const unsigned short* __restrict__ v2t,
                                               float* __restrict__ als,
                                               float* __restrict__ ald,
                                               int M, int Ndst) {
    __shared__ float smu[256], ssc[256], ssh[256];
    {
        int c = threadIdx.x;
        float invM = 1.f / (float)M;
        float mu = stats[c] * invM;
        float var = stats[256 + c] * invM - mu * mu;
        smu[c] = mu;
        ssc[c] = rsqrtf(var + kEPS) * gamma[c];
        ssh[c] = beta[c];
    }
    __syncthreads();

    int wid = threadIdx.x >> 6, lane = threadIdx.x & 63;
    int l15 = lane & 15, l4 = lane >> 4;
    short8 bfr[8];
    if (AL) {
        #pragma unroll
        for (int ks = 0; ks < 8; ++ks)
            bfr[ks] = *reinterpret_cast<const short8*>(&v2t[l15 * 256 + ks * 32 + l4 * 8]);
    }

    const int ntile = M / 16;
    int nw = gridDim.x * 4;
    for (int t = blockIdx.x * 4 + wid; t < ntile; t += nw) {
        int base = t * 16;
        int r = base + l15;
        f32x4 acc = (f32x4){0.f, 0.f, 0.f, 0.f};
        #pragma unroll
        for (int ks = 0; ks < 8; ++ks) {
            int c0 = ks * 32 + l4 * 8;
            size_t o = (size_t)r * 256 + c0;
            short8 xr = *reinterpret_cast<const short8*>(&X[o]);
            float4 mua = *reinterpret_cast<const float4*>(&smu[c0]);
            float4 muc = *reinterpret_cast<const float4*>(&smu[c0 + 4]);
            float4 sca = *reinterpret_cast<const float4*>(&ssc[c0]);
            float4 scc = *reinterpret_cast<const float4*>(&ssc[c0 + 4]);
            float4 sha = *reinterpret_cast<const float4*>(&ssh[c0]);
            float4 shc = *reinterpret_cast<const float4*>(&ssh[c0 + 4]);
            float v[8];
            v[0] = (b2f((unsigned short)xr[0]) - mua.x) * sca.x + sha.x;
            v[1] = (b2f((unsigned short)xr[1]) - mua.y) * sca.y + sha.y;
            v[2] = (b2f((unsigned short)xr[2]) - mua.z) * sca.z + sha.z;
            v[3] = (b2f((unsigned short)xr[3]) - mua.w) * sca.w + sha.w;
            v[4] = (b2f((unsigned short)xr[4]) - muc.x) * scc.x + shc.x;
            v[5] = (b2f((unsigned short)xr[5]) - muc.y) * scc.y + shc.y;
            v[6] = (b2f((unsigned short)xr[6]) - muc.z) * scc.z + shc.z;
            v[7] = (b2f((unsigned short)xr[7]) - muc.w) * scc.w + shc.w;
            short8 af;
            #pragma unroll
            for (int i = 0; i < 8; ++i) {
                float tv = v[i] > 0.f ? v[i] : expm1f(v[i]);
                af[i] = (short)f2bf(tv);
            }
            *reinterpret_cast<short8*>(&outb[o]) = af;
            if (AL) acc = __builtin_amdgcn_mfma_f32_16x16x32_bf16(af, bfr[ks], acc, 0, 0, 0);
        }
        if (AL && l15 < 8) {
            #pragma unroll
            for (int i = 0; i < 4; ++i) {
                int node = base + l4 * 4 + i;
                if (l15 < 4) als[(size_t)node * 4 + l15] = acc[i];
                else if (node < Ndst) ald[(size_t)node * 4 + (l15 - 4)] = acc[i];
            }
        }
    }
}

// ================= CSR scans =================
__global__ __launch_bounds__(256) void scan_block_both(const int* __restrict__ cnt1, int n1,
                                                       int* __restrict__ offs1, int* __restrict__ bsum1, int nb1,
                                                       const int* __restrict__ cnt2, int n2,
                                                       int* __restrict__ offs2, int* __restrict__ bsum2) {
    const int* counts; int n; int* offs; int* bsum; int b;
    if ((int)blockIdx.x < nb1) { counts = cnt1; n = n1; offs = offs1; bsum = bsum1; b = blockIdx.x; }
    else { counts = cnt2; n = n2; offs = offs2; bsum = bsum2; b = blockIdx.x - nb1; }
    __shared__ int sh[256];
    int tid = threadIdx.x;
    int base = b * 1024 + tid * 4;
    int c0 = (base + 0 < n) ? counts[base + 0] : 0;
    int c1 = (base + 1 < n) ? counts[base + 1] : 0;
    int c2 = (base + 2 < n) ? counts[base + 2] : 0;
    int c3 = (base + 3 < n) ? counts[base + 3] : 0;
    int tot = c0 + c1 + c2 + c3;
    sh[tid] = tot;
    __syncthreads();
    for (int o = 1; o < 256; o <<= 1) {
        int t = (tid >= o) ? sh[tid - o] : 0;
        __syncthreads();
        sh[tid] += t;
        __syncthreads();
    }
    int excl = sh[tid] - tot;
    if (base + 0 < n) offs[base + 0] = excl;
    if (base + 1 < n) offs[base + 1] = excl + c0;
    if (base + 2 < n) offs[base + 2] = excl + c0 + c1;
    if (base + 3 < n) offs[base + 3] = excl + c0 + c1 + c2;
    if (tid == 255) bsum[b] = sh[255];
}

// scan_add with inline serial scan of block sums
__global__ __launch_bounds__(256) void scan_add_both(int* __restrict__ offs1,
                                                     const int* __restrict__ bsum1,
                                                     const int* __restrict__ cnt1, int n1, int nb1,
                                                     int* __restrict__ offs2,
                                                     const int* __restrict__ bsum2,
                                                     const int* __restrict__ cnt2, int n2, int nb2) {
    __shared__ int sb1[128], sb2[32];
    if (threadIdx.x == 0) {
        int acc = 0;
        for (int j = 0; j < nb1; ++j) { sb1[j] = acc; acc += bsum1[j]; }
        acc = 0;
        for (int j = 0; j < nb2; ++j) { sb2[j] = acc; acc += bsum2[j]; }
    }
    __syncthreads();
    int i = blockIdx.x * blockDim.x + threadIdx.x;
    if (i < n1) {
        int v = offs1[i] + sb1[i >> 10];
        offs1[i] = v;
        if (i == n1 - 1) offs1[n1] = v + cnt1[i];
    } else {
        int j = i - n1;
        if (j < n2) {
            int v = offs2[j] + sb2[j >> 10];
            offs2[j] = v;
            if (j == n2 - 1) offs2[n2] = v + cnt2[j];
        }
    }
}

// scatter src id + per-edge softmax numerators w[h] = exp(lrelu(als[s]+ald[d]))
__global__ void csr_scatter_w(const int* __restrict__ dst, const int* __restrict__ src,
                              const int* __restrict__ offs,
                              const float* __restrict__ als, const float* __restrict__ ald,
                              int* __restrict__ cur, int* __restrict__ srcs,
                              float4* __restrict__ wbuf, int E) {
    int e = blockIdx.x * blockDim.x + threadIdx.x;
    if (e >= E) return;
    int d = dst[e], s = src[e];
    int pos = offs[d] + atomicAdd(&cur[d], 1);
    srcs[pos] = s;
    float4 a = *reinterpret_cast<const float4*>(&als[(size_t)s * 4]);
    float4 b = *reinterpret_cast<const float4*>(&ald[(size_t)d * 4]);
    float4 w;
    w.x = expf(lrelu(a.x + b.x));
    w.y = expf(lrelu(a.y + b.y));
    w.z = expf(lrelu(a.z + b.z));
    w.w = expf(lrelu(a.w + b.w));
    wbuf[pos] = w;
}

// ================= pipelined bf16 MFMA GEMM, 8 waves, split-A + K-window =================
template <bool OUTBF, bool STATS>
__global__ __launch_bounds__(512) void gemm_pipe(const unsigned short* __restrict__ A1, int K1,
                                                 const unsigned short* __restrict__ A2, int K2,
                                                 const unsigned short* __restrict__ Bt,
                                                 void* __restrict__ Cv,
                                                 const float* __restrict__ bias1,
                                                 const float* __restrict__ bias2,
                                                 float* __restrict__ stats,
                                                 int M, int N, int rs, int kwin) {
    __shared__ unsigned short SH[4][128 * 64];
    const int tid = threadIdx.x;
    const int wid = tid >> 6, lane = tid & 63;
    const int wr = wid >> 2, wc = wid & 3;       // 2 x 4 wave grid; wave = 64 rows x 32 cols
    const int l15 = lane & 15, l4 = lane >> 4;
    const int m0 = blockIdx.y * 128, n0 = blockIdx.x * 128;
    const int rsub = lane >> 3;
    const int kslot = (lane & 7) ^ rsub;
    const int KB = K1 + K2;
    const int nwin = kwin >> 6;
    const int nt = nwin + (K2 >> 6);
    const int wbase = n0 * rs;                   // A1 K-window start for this col-block

    auto stage = [&](int buf, int t) {
        const unsigned short* Asrc; int ka, lda, gk;
        if (t < nwin) { gk = wbase + (t << 6); Asrc = A1; ka = gk; lda = K1; }
        else { int t2 = t - nwin; gk = K1 + (t2 << 6); Asrc = A2; ka = t2 << 6; lda = K2; }
        #pragma unroll
        for (int c = 0; c < 2; ++c) {
            int q = wid * 2 + c;
            int rowA = m0 + q * 8 + rsub; if (rowA > M - 1) rowA = M - 1;
            gload_lds16(Asrc + (size_t)rowA * lda + ka + kslot * 8, &SH[buf][q * 512]);
            int rowB = n0 + q * 8 + rsub;
            gload_lds16(Bt + (size_t)rowB * KB + gk + kslot * 8, &SH[2 + buf][q * 512]);
        }
    };

    f32x4 acc[4][2];
    #pragma unroll
    for (int i = 0; i < 4; ++i)
        #pragma unroll
        for (int j = 0; j < 2; ++j) acc[i][j] = (f32x4){0.f, 0.f, 0.f, 0.f};

    stage(0, 0);
    __syncthreads();
    for (int t = 0; t < nt; ++t) {
        if (t + 1 < nt) stage((t + 1) & 1, t + 1);
        int b = t & 1;
        short8 af[2][4], bf[2][2];
        #pragma unroll
        for (int kk = 0; kk < 2; ++kk) {
            #pragma unroll
            for (int mi = 0; mi < 4; ++mi) {
                int row = wr * 64 + mi * 16 + l15;
                af[kk][mi] = *reinterpret_cast<const short8*>(
                    &SH[b][row * 64 + (((kk * 4 + l4) ^ (row & 7)) << 3)]);
            }
            #pragma unroll
            for (int ni = 0; ni < 2; ++ni) {
                int row = wc * 32 + ni * 16 + l15;
                bf[kk][ni] = *reinterpret_cast<const short8*>(
                    &SH[2 + b][row * 64 + (((kk * 4 + l4) ^ (row & 7)) << 3)]);
            }
        }
        #pragma unroll
        for (int kk = 0; kk < 2; ++kk)
            #pragma unroll
            for (int mi = 0; mi < 4; ++mi)
                #pragma unroll
                for (int ni = 0; ni < 2; ++ni)
                    acc[mi][ni] = __builtin_amdgcn_mfma_f32_16x16x32_bf16(
                        af[kk][mi], bf[kk][ni], acc[mi][ni], 0, 0, 0);
        __syncthreads();
    }

    float csum[2] = {0.f, 0.f}, csq[2] = {0.f, 0.f};
    unsigned short* LB = (unsigned short*)SH;
    float* LF = (float*)SH;
    #pragma unroll
    for (int mi = 0; mi < 4; ++mi) {
        int lrow0 = wr * 64 + mi * 16 + l4 * 4;
        #pragma unroll
        for (int ni = 0; ni < 2; ++ni) {
            int lcol = wc * 32 + ni * 16 + l15;
            int col = n0 + lcol;
            float badd = 0.f;
            if (bias1) badd += bias1[col];
            if (bias2) badd += bias2[col];
            f32x4 v = acc[mi][ni];
            #pragma unroll
            for (int i = 0; i < 4; ++i) {
                float o = v[i] + badd;
                if (STATS && (m0 + lrow0 + i) < M) { csum[ni] += o; csq[ni] += o * o; }
                if (OUTBF) LB[(lrow0 + i) * 128 + lcol] = f2bf(o);
                else LF[(lrow0 + i) * 128 + lcol] = o;
            }
        }
    }
    if (STATS) {
        #pragma unroll
        for (int ni = 0; ni < 2; ++ni) {
            float s = csum[ni], q = csq[ni];
            s += __shfl_xor(s, 16, 64); q += __shfl_xor(q, 16, 64);
            s += __shfl_xor(s, 32, 64); q += __shfl_xor(q, 32, 64);
            if (l4 == 0) {
                int col = n0 + wc * 32 + ni * 16 + l15;
                atomicAdd(&stats[col], s);
                atomicAdd(&stats[256 + col], q);
            }
        }
    }
    __syncthreads();
    if (OUTBF) {
        unsigned short* Cb = (unsigned short*)Cv;
        #pragma unroll
        for (int it = 0; it < 4; ++it) {
            int lin = (it * 512 + tid) * 8;
            int r = lin >> 7, c0 = lin & 127;
            int gr = m0 + r;
            if (gr < M)
                *reinterpret_cast<short8*>(&Cb[(size_t)gr * N + n0 + c0]) =
                    *reinterpret_cast<const short8*>(&LB[lin]);
        }
    } else {
        float* Cf = (float*)Cv;
        #pragma unroll
        for (int it = 0; it < 8; ++it) {
            int lin = (it * 512 + tid) * 4;
            int r = lin >> 7, c0 = lin & 127;
            int gr = m0 + r;
            if (gr < M)
                *reinterpret_cast<float4*>(&Cf[(size_t)gr * N + n0 + c0]) =
                    *reinterpret_cast<const float4*>(&LF[lin]);
        }
    }
}

// ---------------- layer-1 aggregate: predicated 4-group pipeline; NT Agg stores ----------------
__global__ __launch_bounds__(256) void fused_agg1(const unsigned short* __restrict__ xb,
                                                  const float4* __restrict__ wbuf,
                                                  const int* __restrict__ srcs,
                                                  const int* __restrict__ offs,
                                                  unsigned short* __restrict__ Agg, int Ndst) {
    int d = blockIdx.x * 4 + (threadIdx.x >> 6);
    if (d >= Ndst) return;
    int lane = threadIdx.x & 63;
    int beg = offs[d], end = offs[d + 1];
    float ac[4][2] = {};
    float se0 = 0.f, se1 = 0.f, se2 = 0.f, se3 = 0.f;

    for (int i = beg; i < end; i += 4) {
        int s[4]; float4 w[4]; unsigned xv[4];
        #pragma unroll
        for (int j = 0; j < 4; ++j) {
            int idx = i + j < end ? i + j : end - 1;
            s[j] = srcs[idx];
            if (i + j < end) w[j] = wbuf[idx];
            else w[j] = make_float4(0.f, 0.f, 0.f, 0.f);
        }
        #pragma unroll
        for (int j = 0; j < 4; ++j)
            xv[j] = *reinterpret_cast<const unsigned*>(&xb[(size_t)s[j] * 128 + lane * 2]);
        #pragma unroll
        for (int j = 0; j < 4; ++j) {
            se0 += w[j].x; se1 += w[j].y; se2 += w[j].z; se3 += w[j].w;
            float fx = b2f((unsigned short)(xv[j] & 0xffff));
            float fy = b2f((unsigned short)(xv[j] >> 16));
            ac[0][0] = fmaf(w[j].x, fx, ac[0][0]); ac[0][1] = fmaf(w[j].x, fy, ac[0][1]);
            ac[1][0] = fmaf(w[j].y, fx, ac[1][0]); ac[1][1] = fmaf(w[j].y, fy, ac[1][1]);
            ac[2][0] = fmaf(w[j].z, fx, ac[2][0]); ac[2][1] = fmaf(w[j].z, fy, ac[2][1]);
            ac[3][0] = fmaf(w[j].w, fx, ac[3][0]); ac[3][1] = fmaf(w[j].w, fy, ac[3][1]);
        }
    }

    float inv0 = 1.f / (se0 + 1e-16f), inv1 = 1.f / (se1 + 1e-16f);
    float inv2 = 1.f / (se2 + 1e-16f), inv3 = 1.f / (se3 + 1e-16f);
    unsigned short* row = Agg + (size_t)d * 512;
    __builtin_nontemporal_store(pack2(ac[0][0] * inv0, ac[0][1] * inv0),
                                reinterpret_cast<unsigned*>(&row[0 * 128 + lane * 2]));
    __builtin_nontemporal_store(pack2(ac[1][0] * inv1, ac[1][1] * inv1),
                                reinterpret_cast<unsigned*>(&row[1 * 128 + lane * 2]));
    __builtin_nontemporal_store(pack2(ac[2][0] * inv2, ac[2][1] * inv2),
                                reinterpret_cast<unsigned*>(&row[2 * 128 + lane * 2]));
    __builtin_nontemporal_store(pack2(ac[3][0] * inv3, ac[3][1] * inv3),
                                reinterpret_cast<unsigned*>(&row[3 * 128 + lane * 2]));
}

// ---------------- layer-2 aggregate: predicated 4-group pipeline; NT Agg stores ----------------
__global__ __launch_bounds__(256) void fused_agg2(const unsigned short* __restrict__ hb,
                                                  const float4* __restrict__ wbuf,
                                                  const int* __restrict__ srcs,
                                                  const int* __restrict__ offs,
                                                  unsigned short* __restrict__ Agg, int Ndst) {
    int d = blockIdx.x * 4 + (threadIdx.x >> 6);
    if (d >= Ndst) return;
    int lane = threadIdx.x & 63;
    int beg = offs[d], end = offs[d + 1];
    float ac[4][4] = {};
    float se0 = 0.f, se1 = 0.f, se2 = 0.f, se3 = 0.f;

    for (int i = beg; i < end; i += 4) {
        int s[4]; float4 w[4]; ushort4 xv[4];
        #pragma unroll
        for (int j = 0; j < 4; ++j) {
            int idx = i + j < end ? i + j : end - 1;
            s[j] = srcs[idx];
            if (i + j < end) w[j] = wbuf[idx];
            else w[j] = make_float4(0.f, 0.f, 0.f, 0.f);
        }
        #pragma unroll
        for (int j = 0; j < 4; ++j)
            xv[j] = *reinterpret_cast<const ushort4*>(&hb[(size_t)s[j] * 256 + lane * 4]);
        #pragma unroll
        for (int j = 0; j < 4; ++j) {
            se0 += w[j].x; se1 += w[j].y; se2 += w[j].z; se3 += w[j].w;
            float f0 = b2f(xv[j].x), f1 = b2f(xv[j].y), f2 = b2f(xv[j].z), f3 = b2f(xv[j].w);
            ac[0][0] = fmaf(w[j].x, f0, ac[0][0]); ac[0][1] = fmaf(w[j].x, f1, ac[0][1]);
            ac[0][2] = fmaf(w[j].x, f2, ac[0][2]); ac[0][3] = fmaf(w[j].x, f3, ac[0][3]);
            ac[1][0] = fmaf(w[j].y, f0, ac[1][0]); ac[1][1] = fmaf(w[j].y, f1, ac[1][1]);
            ac[1][2] = fmaf(w[j].y, f2, ac[1][2]); ac[1][3] = fmaf(w[j].y, f3, ac[1][3]);
            ac[2][0] = fmaf(w[j].z, f0, ac[2][0]); ac[2][1] = fmaf(w[j].z, f1, ac[2][1]);
            ac[2][2] = fmaf(w[j].z, f2, ac[2][2]); ac[2][3] = fmaf(w[j].z, f3, ac[2][3]);
            ac[3][0] = fmaf(w[j].w, f0, ac[3][0]); ac[3][1] = fmaf(w[j].w, f1, ac[3][1]);
            ac[3][2] = fmaf(w[j].w, f2, ac[3][2]); ac[3][3] = fmaf(w[j].w, f3, ac[3][3]);
        }
    }

    float inv[4] = {1.f / (se0 + 1e-16f), 1.f / (se1 + 1e-16f),
                    1.f / (se2 + 1e-16f), 1.f / (se3 + 1e-16f)};
    unsigned short* row = Agg + (size_t)d * 1024;
    #pragma unroll
    for (int h = 0; h < 4; ++h) {
        __builtin_nontemporal_store(
            pack4(ac[h][0] * inv[h], ac[h][1] * inv[h], ac[h][2] * inv[h], ac[h][3] * inv[h]),
            reinterpret_cast<unsigned long long*>(&row[h * 256 + lane * 4]));
    }
}

// ---------------- fp32 tiled GEMM with fused BN(ReLU) on bf16 A (final N=47 head) ----------------
__global__ __launch_bounds__(256) void gemm64_bn(const unsigned short* __restrict__ A,
                                                 const float* __restrict__ B,
                                                 float* __restrict__ Cmat,
                                                 const float* __restrict__ bias,
                                                 const float* __restrict__ stats,
                                                 const float* __restrict__ gamma,
                                                 const float* __restrict__ beta,
                                                 int M, int N, int K) {
    __shared__ float As[32][68];
    __shared__ float Bs[32][68];
    __shared__ float bnsc[256], bnsh[256];
    const int tid = threadIdx.x;
    {
        int c = tid;
        float invM = 1.f / (float)M;
        float mu = stats[c] * invM;
        float var = stats[256 + c] * invM - mu * mu;
        float sc = rsqrtf(var + kEPS) * gamma[c];
        bnsc[c] = sc;
        bnsh[c] = beta[c] - mu * sc;
    }
    __syncthreads();
    const int tx = tid & 15, ty = tid >> 4;
    const int m0 = blockIdx.y * 64, n0 = blockIdx.x * 64;
    float acc[4][4] = {};

    for (int k0 = 0; k0 < K; k0 += 32) {
        #pragma unroll
        for (int t = 0; t < 2; ++t) {
            int i = tid + t * 256;
            int row = i >> 3;
            int kq = (i & 7) << 2;
            ushort4 u = make_ushort4(0, 0, 0, 0);
            int gr = m0 + row;
            if (gr < M) u = *reinterpret_cast<const ushort4*>(&A[(size_t)gr * K + k0 + kq]);
            #pragma unroll
            for (int j = 0; j < 4; ++j) {
                int k = k0 + kq + j;
                unsigned short uv = (j == 0) ? u.x : (j == 1) ? u.y : (j == 2) ? u.z : u.w;
                float v = b2f(uv) * bnsc[k] + bnsh[k];
                As[kq + j][row] = fmaxf(v, 0.f);
            }
        }
        #pragma unroll
        for (int t = 0; t < 2; ++t) {
            int i = tid + t * 256;
            int kr = i >> 4;
            int cq = (i & 15) << 2;
            #pragma unroll
            for (int j = 0; j < 4; ++j) {
                int gc = n0 + cq + j;
                Bs[kr][cq + j] = (gc < N) ? B[(size_t)(k0 + kr) * N + gc] : 0.f;
            }
        }
        __syncthreads();
        #pragma unroll
        for (int kk = 0; kk < 32; ++kk) {
            float4 a4 = *reinterpret_cast<const float4*>(&As[kk][ty << 2]);
            float4 b4 = *reinterpret_cast<const float4*>(&Bs[kk][tx << 2]);
            float a[4] = {a4.x, a4.y, a4.z, a4.w};
            float b[4] = {b4.x, b4.y, b4.z, b4.w};
            #pragma unroll
            for (int i2 = 0; i2 < 4; ++i2)
                #pragma unroll
                for (int j = 0; j < 4; ++j)
                    acc[i2][j] = fmaf(a[i2], b[j], acc[i2][j]);
        }
        __syncthreads();
    }

    #pragma unroll
    for (int i2 = 0; i2 < 4; ++i2) {
        int row = m0 + (ty << 2) + i2;
        if (row >= M) continue;
        #pragma unroll
        for (int j = 0; j < 4; ++j) {
            int col = n0 + (tx << 2) + j;
            if (col >= N) continue;
            Cmat[(size_t)row * N + col] = acc[i2][j] + bias[col];
        }
    }
}

extern "C" void kernel_launch(void* const* d_in, const int* in_sizes, int n_in,
                              void* d_out, int out_size, void* d_ws, size_t ws_size,
                              hipStream_t stream) {
    (void)in_sizes; (void)n_in; (void)out_size; (void)ws_size;

    const float* x      = (const float*)d_in[0];
    const int*   src1   = (const int*)d_in[1];
    const int*   dst1   = (const int*)d_in[2];
    const int*   src2   = (const int*)d_in[3];
    const int*   dst2   = (const int*)d_in[4];
    const float* W1     = (const float*)d_in[5];
    const float* a_src1 = (const float*)d_in[6];
    const float* a_dst1 = (const float*)d_in[7];
    const float* b1     = (const float*)d_in[8];
    const float* Wsk1   = (const float*)d_in[9];
    const float* bsk1   = (const float*)d_in[10];
    const float* g1     = (const float*)d_in[11];
    const float* be1    = (const float*)d_in[12];
    const float* W2     = (const float*)d_in[13];
    const float* a_src2 = (const float*)d_in[14];
    const float* a_dst2 = (const float*)d_in[15];
    const float* b2     = (const float*)d_in[16];
    const float* Wsk2   = (const float*)d_in[17];
    const float* bsk2   = (const float*)d_in[18];
    const float* g2     = (const float*)d_in[19];
    const float* be2    = (const float*)d_in[20];
    const float* Wm1    = (const float*)d_in[21];
    const float* bm1    = (const float*)d_in[22];
    const float* gm     = (const float*)d_in[23];
    const float* bem    = (const float*)d_in[24];
    const float* Wm2    = (const float*)d_in[25];
    const float* bm2    = (const float*)d_in[26];

    // ---- workspace layout (float units; all chunks 16B-aligned) ----
    float* ws = (float*)d_ws;
    size_t off = 0;
    auto alloc = [&](size_t n) { float* p = ws + off; off += n; return p; };
    unsigned short* xb    = (unsigned short*)alloc((size_t)kN0 * 128 / 2);
    unsigned short* Agg1  = (unsigned short*)alloc((size_t)kN1 * 512 / 2);
    unsigned short* Agg2  = (unsigned short*)alloc((size_t)kN2 * 1024 / 2);
    unsigned short* h1pre = (unsigned short*)alloc((size_t)kN1 * 256 / 2);
    unsigned short* h1b   = (unsigned short*)alloc((size_t)kN1 * 256 / 2);
    unsigned short* h2pre = (unsigned short*)alloc((size_t)kN2 * 256 / 2);
    unsigned short* h2b   = (unsigned short*)alloc((size_t)kN2 * 256 / 2);
    unsigned short* h3pre = (unsigned short*)alloc((size_t)kN2 * 256 / 2);
    unsigned short* Wcat1t = (unsigned short*)alloc(256 * 640 / 2);
    unsigned short* Wcat2t = (unsigned short*)alloc(256 * 1280 / 2);
    unsigned short* Wm1t   = (unsigned short*)alloc(256 * 256 / 2);
    unsigned short* v1t    = (unsigned short*)alloc(16 * 128 / 2);
    unsigned short* v2t    = (unsigned short*)alloc(16 * 256 / 2);
    float4* w1buf = (float4*)alloc((size_t)kE1 * 4);
    float4* w2buf = (float4*)alloc((size_t)kE2 * 4);
    float* als1 = alloc((size_t)kN0 * 4);
    float* ald1 = alloc((size_t)kN1 * 4);
    float* als2 = alloc((size_t)kN1 * 4);
    float* ald2 = alloc((size_t)kN2 * 4);
    float* zreg = alloc(kNZreg);
    float* stats1 = zreg, *stats2 = zreg + 512, *stats3 = zreg + 1024;
    int* cnt1 = (int*)(zreg + 1536);
    int* cur1 = cnt1 + kN1;
    int* cnt2 = cur1 + kN1;
    int* cur2 = cnt2 + kN2;
    int* srcs1  = (int*)alloc(kE1);
    int* offs1  = (int*)alloc(kN1 + 4);
    int* bsum1  = (int*)alloc(128);
    int* srcs2  = (int*)alloc(kE2);
    int* offs2  = (int*)alloc(kN2 + 4);
    int* bsum2  = (int*)alloc(128);

    hipStream_t st = stream;
    const int nb1 = (kN1 + 1023) / 1024;   // 98
    const int nb2 = (kN2 + 1023) / 1024;   // 20

    // ---- init + precomputes (single launch) ----
    prep_all<<<(kNZreg + 563200 + 255) / 256, 256, 0, st>>>(
        W1, a_src1, a_dst1, W2, a_src2, a_dst2, Wsk1, Wsk2, Wm1,
        zreg, v1t, v2t, Wcat1t, Wcat2t, Wm1t);

    // ---- dst histograms (standalone) ----
    hist_both<<<(kE1 + kE2 + 255) / 256, 256, 0, st>>>(dst1, cnt1, dst2, cnt2);

    // ---- x -> bf16 + layer-1 attention dots (pure streaming) ----
    conv_als<<<kN0 / 64, 256, 0, st>>>(x, v1t, xb, als1, ald1);

    // ---- CSR scans ----
    scan_block_both<<<nb1 + nb2, 256, 0, st>>>(cnt1, kN1, offs1, bsum1, nb1, cnt2, kN2, offs2, bsum2);
    scan_add_both<<<(kN1 + kN2 + 255) / 256, 256, 0, st>>>(offs1, bsum1, cnt1, kN1, nb1,
                                                           offs2, bsum2, cnt2, kN2, nb2);
    csr_scatter_w<<<(kE1 + 255) / 256, 256, 0, st>>>(dst1, src1, offs1, als1, ald1,
                                                     cur1, srcs1, w1buf, kE1);

    // ================= layer 1 =================
    fused_agg1<<<(kN1 + 3) / 4, 256, 0, st>>>(xb, w1buf, srcs1, offs1, Agg1, kN1);
    gemm_pipe<true, true><<<dim3(2, (kN1 + 127) / 128), 512, 0, st>>>(
        Agg1, 512, xb, 128, Wcat1t, h1pre, b1, bsk1, stats1, kN1, 256, /*rs=*/2, /*kwin=*/256);
    bn_mfma<true><<<1024, 256, 0, st>>>(h1pre, stats1, g1, be1, h1b, v2t, als2, ald2, kN1, kN2);

    // ================= layer 2 =================
    csr_scatter_w<<<(kE2 + 255) / 256, 256, 0, st>>>(dst2, src2, offs2, als2, ald2,
                                                     cur2, srcs2, w2buf, kE2);
    fused_agg2<<<(kN2 + 3) / 4, 256, 0, st>>>(h1b, w2buf, srcs2, offs2, Agg2, kN2);
    gemm_pipe<true, true><<<dim3(2, (kN2 + 127) / 128), 512, 0, st>>>(
        Agg2, 1024, h1b, 256, Wcat2t, h2pre, b2, bsk2, stats2, kN2, 256, /*rs=*/4, /*kwin=*/512);
    bn_mfma<false><<<1024, 256, 0, st>>>(h2pre, stats2, g2, be2, h2b, nullptr, nullptr, nullptr,
                                         kN2, 0);

    // ================= MLP head =================
    gemm_pipe<true, true><<<dim3(2, (kN2 + 127) / 128), 512, 0, st>>>(
        h2b, 256, nullptr, 0, Wm1t, h3pre, bm1, nullptr, stats3, kN2, 256, /*rs=*/0, /*kwin=*/256);
    gemm64_bn<<<dim3(1, (kN2 + 63) / 64), 256, 0, st>>>(
        h3pre, Wm2, (float*)d_out, bm2, stats3, gm, bem, kN2, kOUT, 256);
}

// Round 19
// 513.231 us; speedup vs baseline: 1.0254x; 1.0254x over previous
//
#include <hip/hip_runtime.h>
#include <math.h>

// Problem constants (fixed by the reference)
constexpr int kN0 = 400000, kN1 = 100000, kN2 = 20000;
constexpr int kE1 = 1000000, kE2 = 200000;
constexpr int kIN = 128, kHID = 256, kOUT = 47;
constexpr float kEPS = 1e-5f, kNEG = 0.2f;

#define DEV static __device__ __forceinline__

typedef __attribute__((ext_vector_type(8))) short short8;
typedef __attribute__((ext_vector_type(4))) float f32x4;

DEV float b2f(unsigned short u) { return __uint_as_float(((unsigned)u) << 16); }
DEV unsigned short f2bf(float f) {
    unsigned u = __float_as_uint(f);
    unsigned r = (u + 0x7fffu + ((u >> 16) & 1u)) >> 16;   // RNE
    return (unsigned short)r;
}
DEV float lrelu(float v) { return v > 0.f ? v : kNEG * v; }

DEV void gload_lds16(const void* g, void* l) {
    __builtin_amdgcn_global_load_lds(
        (const __attribute__((address_space(1))) void*)g,
        (__attribute__((address_space(3))) void*)l, 16, 0, 0);
}

DEV unsigned pack2(float a, float b) {
    return (unsigned)f2bf(a) | ((unsigned)f2bf(b) << 16);
}
DEV unsigned long long pack4(float a, float b, float c, float d) {
    return (unsigned long long)pack2(a, b) | ((unsigned long long)pack2(c, d) << 32);
}

// ---- merged init: zero zreg + weight precompute (v1t, v2t, Wcat1t, Wcat2t, Wm1t) ----
constexpr int kNZreg = 1536 + 2 * kN1 + 2 * kN2;   // 241536
__global__ void prep_all(const float* __restrict__ W1, const float* __restrict__ as1,
                         const float* __restrict__ ad1,
                         const float* __restrict__ W2, const float* __restrict__ as2,
                         const float* __restrict__ ad2,
                         const float* __restrict__ Wsk1, const float* __restrict__ Wsk2,
                         const float* __restrict__ Wm1,
                         float* __restrict__ zreg,
                         unsigned short* __restrict__ v1t, unsigned short* __restrict__ v2t,
                         unsigned short* __restrict__ Wcat1t,
                         unsigned short* __restrict__ Wcat2t,
                         unsigned short* __restrict__ Wm1t) {
    int i = blockIdx.x * blockDim.x + threadIdx.x;
    if (i < kNZreg) { zreg[i] = 0.f; return; }
    i -= kNZreg;
    if (i < 2048) {                       // v1t[16][128]
        int j = i >> 7, k = i & 127;
        float s = 0.f;
        if (j < 8) {
            int h = j & 3;
            const float* a = (j >= 4) ? ad1 : as1;
            for (int c = 0; c < 64; ++c) s += W1[(size_t)k * 256 + h * 64 + c] * a[h * 64 + c];
        }
        v1t[i] = f2bf(s);
        return;
    }
    i -= 2048;
    if (i < 4096) {                       // v2t[16][256]
        int j = i >> 8, k = i & 255;
        float s = 0.f;
        if (j < 8) {
            int h = j & 3;
            const float* a = (j >= 4) ? ad2 : as2;
            for (int c = 0; c < 64; ++c) s += W2[(size_t)k * 256 + h * 64 + c] * a[h * 64 + c];
        }
        v2t[i] = f2bf(s);
        return;
    }
    i -= 4096;
    if (i < 163840) {                     // Wcat1t[256][640]
        int n = i / 640, k = i % 640;
        float v;
        if (k < 512) { int h = k >> 7, kin = k & 127; v = ((n >> 6) == h) ? W1[(size_t)kin * 256 + n] : 0.f; }
        else v = Wsk1[(size_t)(k - 512) * 256 + n];
        Wcat1t[i] = f2bf(v);
        return;
    }
    i -= 163840;
    if (i < 327680) {                     // Wcat2t[256][1280]
        int n = i / 1280, k = i % 1280;
        float v;
        if (k < 1024) { int h = k >> 8, kin = k & 255; v = ((n >> 6) == h) ? W2[(size_t)kin * 256 + n] : 0.f; }
        else v = Wsk2[(size_t)(k - 1024) * 256 + n];
        Wcat2t[i] = f2bf(v);
        return;
    }
    i -= 327680;
    if (i < 65536) {                      // Wm1t[256][256]
        int n = i >> 8, k = i & 255;
        Wm1t[i] = f2bf(Wm1[(size_t)k * 256 + n]);
    }
}

// ---- merged: x->bf16 (linear R/W) + layer-1 dots via LDS-redistributed MFMA
//      || dst histogram (both layers, trailing blocks) ----
// Block = 4 waves = 64 rows. Phase 1: linear coalesced read/convert/write + swizzled LDS
// stage. Phase 2: ds_read MFMA fragments (same XOR involution) + dots.
__global__ __launch_bounds__(256) void conv_als_hist(const float* __restrict__ x,
                                                     const unsigned short* __restrict__ v1t,
                                                     unsigned short* __restrict__ xb,
                                                     float* __restrict__ als,
                                                     float* __restrict__ ald,
                                                     const int* __restrict__ dst1,
                                                     int* __restrict__ cnt1,
                                                     const int* __restrict__ dst2,
                                                     int* __restrict__ cnt2,
                                                     int convBlocks) {
    if ((int)blockIdx.x >= convBlocks) {
        int e = ((int)blockIdx.x - convBlocks) * 256 + threadIdx.x;
        if (e < kE1) atomicAdd(&cnt1[dst1[e]], 1);
        else { e -= kE1; if (e < kE2) atomicAdd(&cnt2[dst2[e]], 1); }
        return;
    }
    __shared__ unsigned short lds[64 * 128];   // 16 KB
    const int tid = threadIdx.x;
    const int base = (int)blockIdx.x * 64;     // first row of this block

    // ---- phase 1: linear read x, convert, linear write xb, swizzled LDS stage ----
    #pragma unroll
    for (int j = 0; j < 4; ++j) {
        int u = j * 256 + tid;                 // ushort8 slot index, 0..1023
        int row = u >> 4, g = u & 15;
        size_t fo = (size_t)(base + row) * 128 + g * 8;
        float4 xa = *reinterpret_cast<const float4*>(&x[fo]);
        float4 xc = *reinterpret_cast<const float4*>(&x[fo + 4]);
        short8 af;
        af[0] = (short)f2bf(xa.x); af[1] = (short)f2bf(xa.y);
        af[2] = (short)f2bf(xa.z); af[3] = (short)f2bf(xa.w);
        af[4] = (short)f2bf(xc.x); af[5] = (short)f2bf(xc.y);
        af[6] = (short)f2bf(xc.z); af[7] = (short)f2bf(xc.w);
        *reinterpret_cast<short8*>(&xb[fo]) = af;                       // linear, coalesced
        int gs = g ^ (row & 7);                                         // bank-spread involution
        *reinterpret_cast<short8*>(&lds[row * 128 + gs * 8]) = af;
    }
    __syncthreads();

    // ---- phase 2: MFMA dots from LDS fragments ----
    int wid = tid >> 6, lane = tid & 63;
    int l15 = lane & 15, l4 = lane >> 4;
    short8 bfr[4];
    #pragma unroll
    for (int ks = 0; ks < 4; ++ks)
        bfr[ks] = *reinterpret_cast<const short8*>(&v1t[l15 * 128 + ks * 32 + l4 * 8]);

    int rl = wid * 16 + l15;                   // local row for A fragment
    f32x4 acc = (f32x4){0.f, 0.f, 0.f, 0.f};
    #pragma unroll
    for (int ks = 0; ks < 4; ++ks) {
        int g0 = ks * 4 + l4;
        int gs = g0 ^ (rl & 7);
        short8 af = *reinterpret_cast<const short8*>(&lds[rl * 128 + gs * 8]);
        acc = __builtin_amdgcn_mfma_f32_16x16x32_bf16(af, bfr[ks], acc, 0, 0, 0);
    }
    if (l15 < 8) {
        int tilebase = base + wid * 16;
        #pragma unroll
        for (int i = 0; i < 4; ++i) {
            int node = tilebase + l4 * 4 + i;
            if (l15 < 4) als[(size_t)node * 4 + l15] = acc[i];
            else if (node < kN1) ald[(size_t)node * 4 + (l15 - 4)] = acc[i];
        }
    }
}

// ---- fused BN(ELU) bf16->bf16 (+ optional layer-2 attention dots via MFMA) ----
template <bool AL>
__global__ __launch_bounds__(256) void bn_mfma(const unsigned short* __restrict__ X,
                                               const float* __restrict__ stats,
                                               const float* __restrict__ gamma,
                                               const float* __restrict__ beta,
                                               unsigned short* __restrict__ outb,
                                               const unsigned short* __restrict__ v2t,
                                               float* __restrict__ als,
                                               float* __restrict__ ald,
                                               int M, int Ndst) {
    __shared__ float smu[256], ssc[256], ssh[256];
    {
        int c = threadIdx.x;
        float invM = 1.f / (float)M;
        float mu = stats[c] * invM;
        float var = stats[256 + c] * invM - mu * mu;
        smu[c] = mu;
        ssc[c] = rsqrtf(var + kEPS) * gamma[c];
        ssh[c] = beta[c];
    }
    __syncthreads();

    int wid = threadIdx.x >> 6, lane = threadIdx.x & 63;
    int l15 = lane & 15, l4 = lane >> 4;
    short8 bfr[8];
    if (AL) {
        #pragma unroll
        for (int ks = 0; ks < 8; ++ks)
            bfr[ks] = *reinterpret_cast<const short8*>(&v2t[l15 * 256 + ks * 32 + l4 * 8]);
    }

    const int ntile = M / 16;
    int nw = gridDim.x * 4;
    for (int t = blockIdx.x * 4 + wid; t < ntile; t += nw) {
        int base = t * 16;
        int r = base + l15;
        f32x4 acc = (f32x4){0.f, 0.f, 0.f, 0.f};
        #pragma unroll
        for (int ks = 0; ks < 8; ++ks) {
            int c0 = ks * 32 + l4 * 8;
            size_t o = (size_t)r * 256 + c0;
            short8 xr = *reinterpret_cast<const short8*>(&X[o]);
            float4 mua = *reinterpret_cast<const float4*>(&smu[c0]);
            float4 muc = *reinterpret_cast<const float4*>(&smu[c0 + 4]);
            float4 sca = *reinterpret_cast<const float4*>(&ssc[c0]);
            float4 scc = *reinterpret_cast<const float4*>(&ssc[c0 + 4]);
            float4 sha = *reinterpret_cast<const float4*>(&ssh[c0]);
            float4 shc = *reinterpret_cast<const float4*>(&ssh[c0 + 4]);
            float v[8];
            v[0] = (b2f((unsigned short)xr[0]) - mua.x) * sca.x + sha.x;
            v[1] = (b2f((unsigned short)xr[1]) - mua.y) * sca.y + sha.y;
            v[2] = (b2f((unsigned short)xr[2]) - mua.z) * sca.z + sha.z;
            v[3] = (b2f((unsigned short)xr[3]) - mua.w) * sca.w + sha.w;
            v[4] = (b2f((unsigned short)xr[4]) - muc.x) * scc.x + shc.x;
            v[5] = (b2f((unsigned short)xr[5]) - muc.y) * scc.y + shc.y;
            v[6] = (b2f((unsigned short)xr[6]) - muc.z) * scc.z + shc.z;
            v[7] = (b2f((unsigned short)xr[7]) - muc.w) * scc.w + shc.w;
            short8 af;
            #pragma unroll
            for (int i = 0; i < 8; ++i) {
                float tv = v[i] > 0.f ? v[i] : expm1f(v[i]);
                af[i] = (short)f2bf(tv);
            }
            *reinterpret_cast<short8*>(&outb[o]) = af;
            if (AL) acc = __builtin_amdgcn_mfma_f32_16x16x32_bf16(af, bfr[ks], acc, 0, 0, 0);
        }
        if (AL && l15 < 8) {
            #pragma unroll
            for (int i = 0; i < 4; ++i) {
                int node = base + l4 * 4 + i;
                if (l15 < 4) als[(size_t)node * 4 + l15] = acc[i];
                else if (node < Ndst) ald[(size_t)node * 4 + (l15 - 4)] = acc[i];
            }
        }
    }
}

// ================= CSR scans =================
__global__ __launch_bounds__(256) void scan_block_both(const int* __restrict__ cnt1, int n1,
                                                       int* __restrict__ offs1, int* __restrict__ bsum1, int nb1,
                                                       const int* __restrict__ cnt2, int n2,
                                                       int* __restrict__ offs2, int* __restrict__ bsum2) {
    const int* counts; int n; int* offs; int* bsum; int b;
    if ((int)blockIdx.x < nb1) { counts = cnt1; n = n1; offs = offs1; bsum = bsum1; b = blockIdx.x; }
    else { counts = cnt2; n = n2; offs = offs2; bsum = bsum2; b = blockIdx.x - nb1; }
    __shared__ int sh[256];
    int tid = threadIdx.x;
    int base = b * 1024 + tid * 4;
    int c0 = (base + 0 < n) ? counts[base + 0] : 0;
    int c1 = (base + 1 < n) ? counts[base + 1] : 0;
    int c2 = (base + 2 < n) ? counts[base + 2] : 0;
    int c3 = (base + 3 < n) ? counts[base + 3] : 0;
    int tot = c0 + c1 + c2 + c3;
    sh[tid] = tot;
    __syncthreads();
    for (int o = 1; o < 256; o <<= 1) {
        int t = (tid >= o) ? sh[tid - o] : 0;
        __syncthreads();
        sh[tid] += t;
        __syncthreads();
    }
    int excl = sh[tid] - tot;
    if (base + 0 < n) offs[base + 0] = excl;
    if (base + 1 < n) offs[base + 1] = excl + c0;
    if (base + 2 < n) offs[base + 2] = excl + c0 + c1;
    if (base + 3 < n) offs[base + 3] = excl + c0 + c1 + c2;
    if (tid == 255) bsum[b] = sh[255];
}

// scan_add with inline serial scan of block sums
__global__ __launch_bounds__(256) void scan_add_both(int* __restrict__ offs1,
                                                     const int* __restrict__ bsum1,
                                                     const int* __restrict__ cnt1, int n1, int nb1,
                                                     int* __restrict__ offs2,
                                                     const int* __restrict__ bsum2,
                                                     const int* __restrict__ cnt2, int n2, int nb2) {
    __shared__ int sb1[128], sb2[32];
    if (threadIdx.x == 0) {
        int acc = 0;
        for (int j = 0; j < nb1; ++j) { sb1[j] = acc; acc += bsum1[j]; }
        acc = 0;
        for (int j = 0; j < nb2; ++j) { sb2[j] = acc; acc += bsum2[j]; }
    }
    __syncthreads();
    int i = blockIdx.x * blockDim.x + threadIdx.x;
    if (i < n1) {
        int v = offs1[i] + sb1[i >> 10];
        offs1[i] = v;
        if (i == n1 - 1) offs1[n1] = v + cnt1[i];
    } else {
        int j = i - n1;
        if (j < n2) {
            int v = offs2[j] + sb2[j >> 10];
            offs2[j] = v;
            if (j == n2 - 1) offs2[n2] = v + cnt2[j];
        }
    }
}

// scatter src id + per-edge softmax numerators w[h] = exp(lrelu(als[s]+ald[d]))
__global__ void csr_scatter_w(const int* __restrict__ dst, const int* __restrict__ src,
                              const int* __restrict__ offs,
                              const float* __restrict__ als, const float* __restrict__ ald,
                              int* __restrict__ cur, int* __restrict__ srcs,
                              float4* __restrict__ wbuf, int E) {
    int e = blockIdx.x * blockDim.x + threadIdx.x;
    if (e >= E) return;
    int d = dst[e], s = src[e];
    int pos = offs[d] + atomicAdd(&cur[d], 1);
    srcs[pos] = s;
    float4 a = *reinterpret_cast<const float4*>(&als[(size_t)s * 4]);
    float4 b = *reinterpret_cast<const float4*>(&ald[(size_t)d * 4]);
    float4 w;
    w.x = expf(lrelu(a.x + b.x));
    w.y = expf(lrelu(a.y + b.y));
    w.z = expf(lrelu(a.z + b.z));
    w.w = expf(lrelu(a.w + b.w));
    wbuf[pos] = w;
}

// ================= pipelined bf16 MFMA GEMM, 8 waves, split-A + K-window =================
template <bool OUTBF, bool STATS>
__global__ __launch_bounds__(512) void gemm_pipe(const unsigned short* __restrict__ A1, int K1,
                                                 const unsigned short* __restrict__ A2, int K2,
                                                 const unsigned short* __restrict__ Bt,
                                                 void* __restrict__ Cv,
                                                 const float* __restrict__ bias1,
                                                 const float* __restrict__ bias2,
                                                 float* __restrict__ stats,
                                                 int M, int N, int rs, int kwin) {
    __shared__ unsigned short SH[4][128 * 64];
    const int tid = threadIdx.x;
    const int wid = tid >> 6, lane = tid & 63;
    const int wr = wid >> 2, wc = wid & 3;       // 2 x 4 wave grid; wave = 64 rows x 32 cols
    const int l15 = lane & 15, l4 = lane >> 4;
    const int m0 = blockIdx.y * 128, n0 = blockIdx.x * 128;
    const int rsub = lane >> 3;
    const int kslot = (lane & 7) ^ rsub;
    const int KB = K1 + K2;
    const int nwin = kwin >> 6;
    const int nt = nwin + (K2 >> 6);
    const int wbase = n0 * rs;                   // A1 K-window start for this col-block

    auto stage = [&](int buf, int t) {
        const unsigned short* Asrc; int ka, lda, gk;
        if (t < nwin) { gk = wbase + (t << 6); Asrc = A1; ka = gk; lda = K1; }
        else { int t2 = t - nwin; gk = K1 + (t2 << 6); Asrc = A2; ka = t2 << 6; lda = K2; }
        #pragma unroll
        for (int c = 0; c < 2; ++c) {
            int q = wid * 2 + c;
            int rowA = m0 + q * 8 + rsub; if (rowA > M - 1) rowA = M - 1;
            gload_lds16(Asrc + (size_t)rowA * lda + ka + kslot * 8, &SH[buf][q * 512]);
            int rowB = n0 + q * 8 + rsub;
            gload_lds16(Bt + (size_t)rowB * KB + gk + kslot * 8, &SH[2 + buf][q * 512]);
        }
    };

    f32x4 acc[4][2];
    #pragma unroll
    for (int i = 0; i < 4; ++i)
        #pragma unroll
        for (int j = 0; j < 2; ++j) acc[i][j] = (f32x4){0.f, 0.f, 0.f, 0.f};

    stage(0, 0);
    __syncthreads();
    for (int t = 0; t < nt; ++t) {
        if (t + 1 < nt) stage((t + 1) & 1, t + 1);
        int b = t & 1;
        short8 af[2][4], bf[2][2];
        #pragma unroll
        for (int kk = 0; kk < 2; ++kk) {
            #pragma unroll
            for (int mi = 0; mi < 4; ++mi) {
                int row = wr * 64 + mi * 16 + l15;
                af[kk][mi] = *reinterpret_cast<const short8*>(
                    &SH[b][row * 64 + (((kk * 4 + l4) ^ (row & 7)) << 3)]);
            }
            #pragma unroll
            for (int ni = 0; ni < 2; ++ni) {
                int row = wc * 32 + ni * 16 + l15;
                bf[kk][ni] = *reinterpret_cast<const short8*>(
                    &SH[2 + b][row * 64 + (((kk * 4 + l4) ^ (row & 7)) << 3)]);
            }
        }
        #pragma unroll
        for (int kk = 0; kk < 2; ++kk)
            #pragma unroll
            for (int mi = 0; mi < 4; ++mi)
                #pragma unroll
                for (int ni = 0; ni < 2; ++ni)
                    acc[mi][ni] = __builtin_amdgcn_mfma_f32_16x16x32_bf16(
                        af[kk][mi], bf[kk][ni], acc[mi][ni], 0, 0, 0);
        __syncthreads();
    }

    float csum[2] = {0.f, 0.f}, csq[2] = {0.f, 0.f};
    unsigned short* LB = (unsigned short*)SH;
    float* LF = (float*)SH;
    #pragma unroll
    for (int mi = 0; mi < 4; ++mi) {
        int lrow0 = wr * 64 + mi * 16 + l4 * 4;
        #pragma unroll
        for (int ni = 0; ni < 2; ++ni) {
            int lcol = wc * 32 + ni * 16 + l15;
            int col = n0 + lcol;
            float badd = 0.f;
            if (bias1) badd += bias1[col];
            if (bias2) badd += bias2[col];
            f32x4 v = acc[mi][ni];
            #pragma unroll
            for (int i = 0; i < 4; ++i) {
                float o = v[i] + badd;
                if (STATS && (m0 + lrow0 + i) < M) { csum[ni] += o; csq[ni] += o * o; }
                if (OUTBF) LB[(lrow0 + i) * 128 + lcol] = f2bf(o);
                else LF[(lrow0 + i) * 128 + lcol] = o;
            }
        }
    }
    if (STATS) {
        #pragma unroll
        for (int ni = 0; ni < 2; ++ni) {
            float s = csum[ni], q = csq[ni];
            s += __shfl_xor(s, 16, 64); q += __shfl_xor(q, 16, 64);
            s += __shfl_xor(s, 32, 64); q += __shfl_xor(q, 32, 64);
            if (l4 == 0) {
                int col = n0 + wc * 32 + ni * 16 + l15;
                atomicAdd(&stats[col], s);
                atomicAdd(&stats[256 + col], q);
            }
        }
    }
    __syncthreads();
    if (OUTBF) {
        unsigned short* Cb = (unsigned short*)Cv;
        #pragma unroll
        for (int it = 0; it < 4; ++it) {
            int lin = (it * 512 + tid) * 8;
            int r = lin >> 7, c0 = lin & 127;
            int gr = m0 + r;
            if (gr < M)
                *reinterpret_cast<short8*>(&Cb[(size_t)gr * N + n0 + c0]) =
                    *reinterpret_cast<const short8*>(&LB[lin]);
        }
    } else {
        float* Cf = (float*)Cv;
        #pragma unroll
        for (int it = 0; it < 8; ++it) {
            int lin = (it * 512 + tid) * 4;
            int r = lin >> 7, c0 = lin & 127;
            int gr = m0 + r;
            if (gr < M)
                *reinterpret_cast<float4*>(&Cf[(size_t)gr * N + n0 + c0]) =
                    *reinterpret_cast<const float4*>(&LF[lin]);
        }
    }
}

// ---------------- layer-1 aggregate: predicated 4-group pipeline; NT Agg stores ----------------
__global__ __launch_bounds__(256) void fused_agg1(const unsigned short* __restrict__ xb,
                                                  const float4* __restrict__ wbuf,
                                                  const int* __restrict__ srcs,
                                                  const int* __restrict__ offs,
                                                  unsigned short* __restrict__ Agg, int Ndst) {
    int d = blockIdx.x * 4 + (threadIdx.x >> 6);
    if (d >= Ndst) return;
    int lane = threadIdx.x & 63;
    int beg = offs[d], end = offs[d + 1];
    float ac[4][2] = {};
    float se0 = 0.f, se1 = 0.f, se2 = 0.f, se3 = 0.f;

    for (int i = beg; i < end; i += 4) {
        int s[4]; float4 w[4]; unsigned xv[4];
        #pragma unroll
        for (int j = 0; j < 4; ++j) {
            int idx = i + j < end ? i + j : end - 1;
            s[j] = srcs[idx];
            if (i + j < end) w[j] = wbuf[idx];
            else w[j] = make_float4(0.f, 0.f, 0.f, 0.f);
        }
        #pragma unroll
        for (int j = 0; j < 4; ++j)
            xv[j] = *reinterpret_cast<const unsigned*>(&xb[(size_t)s[j] * 128 + lane * 2]);
        #pragma unroll
        for (int j = 0; j < 4; ++j) {
            se0 += w[j].x; se1 += w[j].y; se2 += w[j].z; se3 += w[j].w;
            float fx = b2f((unsigned short)(xv[j] & 0xffff));
            float fy = b2f((unsigned short)(xv[j] >> 16));
            ac[0][0] = fmaf(w[j].x, fx, ac[0][0]); ac[0][1] = fmaf(w[j].x, fy, ac[0][1]);
            ac[1][0] = fmaf(w[j].y, fx, ac[1][0]); ac[1][1] = fmaf(w[j].y, fy, ac[1][1]);
            ac[2][0] = fmaf(w[j].z, fx, ac[2][0]); ac[2][1] = fmaf(w[j].z, fy, ac[2][1]);
            ac[3][0] = fmaf(w[j].w, fx, ac[3][0]); ac[3][1] = fmaf(w[j].w, fy, ac[3][1]);
        }
    }

    float inv0 = 1.f / (se0 + 1e-16f), inv1 = 1.f / (se1 + 1e-16f);
    float inv2 = 1.f / (se2 + 1e-16f), inv3 = 1.f / (se3 + 1e-16f);
    unsigned short* row = Agg + (size_t)d * 512;
    __builtin_nontemporal_store(pack2(ac[0][0] * inv0, ac[0][1] * inv0),
                                reinterpret_cast<unsigned*>(&row[0 * 128 + lane * 2]));
    __builtin_nontemporal_store(pack2(ac[1][0] * inv1, ac[1][1] * inv1),
                                reinterpret_cast<unsigned*>(&row[1 * 128 + lane * 2]));
    __builtin_nontemporal_store(pack2(ac[2][0] * inv2, ac[2][1] * inv2),
                                reinterpret_cast<unsigned*>(&row[2 * 128 + lane * 2]));
    __builtin_nontemporal_store(pack2(ac[3][0] * inv3, ac[3][1] * inv3),
                                reinterpret_cast<unsigned*>(&row[3 * 128 + lane * 2]));
}

// ---------------- layer-2 aggregate: predicated 4-group pipeline; NT Agg stores ----------------
__global__ __launch_bounds__(256) void fused_agg2(const unsigned short* __restrict__ hb,
                                                  const float4* __restrict__ wbuf,
                                                  const int* __restrict__ srcs,
                                                  const int* __restrict__ offs,
                                                  unsigned short* __restrict__ Agg, int Ndst) {
    int d = blockIdx.x * 4 + (threadIdx.x >> 6);
    if (d >= Ndst) return;
    int lane = threadIdx.x & 63;
    int beg = offs[d], end = offs[d + 1];
    float ac[4][4] = {};
    float se0 = 0.f, se1 = 0.f, se2 = 0.f, se3 = 0.f;

    for (int i = beg; i < end; i += 4) {
        int s[4]; float4 w[4]; ushort4 xv[4];
        #pragma unroll
        for (int j = 0; j < 4; ++j) {
            int idx = i + j < end ? i + j : end - 1;
            s[j] = srcs[idx];
            if (i + j < end) w[j] = wbuf[idx];
            else w[j] = make_float4(0.f, 0.f, 0.f, 0.f);
        }
        #pragma unroll
        for (int j = 0; j < 4; ++j)
            xv[j] = *reinterpret_cast<const ushort4*>(&hb[(size_t)s[j] * 256 + lane * 4]);
        #pragma unroll
        for (int j = 0; j < 4; ++j) {
            se0 += w[j].x; se1 += w[j].y; se2 += w[j].z; se3 += w[j].w;
            float f0 = b2f(xv[j].x), f1 = b2f(xv[j].y), f2 = b2f(xv[j].z), f3 = b2f(xv[j].w);
            ac[0][0] = fmaf(w[j].x, f0, ac[0][0]); ac[0][1] = fmaf(w[j].x, f1, ac[0][1]);
            ac[0][2] = fmaf(w[j].x, f2, ac[0][2]); ac[0][3] = fmaf(w[j].x, f3, ac[0][3]);
            ac[1][0] = fmaf(w[j].y, f0, ac[1][0]); ac[1][1] = fmaf(w[j].y, f1, ac[1][1]);
            ac[1][2] = fmaf(w[j].y, f2, ac[1][2]); ac[1][3] = fmaf(w[j].y, f3, ac[1][3]);
            ac[2][0] = fmaf(w[j].z, f0, ac[2][0]); ac[2][1] = fmaf(w[j].z, f1, ac[2][1]);
            ac[2][2] = fmaf(w[j].z, f2, ac[2][2]); ac[2][3] = fmaf(w[j].z, f3, ac[2][3]);
            ac[3][0] = fmaf(w[j].w, f0, ac[3][0]); ac[3][1] = fmaf(w[j].w, f1, ac[3][1]);
            ac[3][2] = fmaf(w[j].w, f2, ac[3][2]); ac[3][3] = fmaf(w[j].w, f3, ac[3][3]);
        }
    }

    float inv[4] = {1.f / (se0 + 1e-16f), 1.f / (se1 + 1e-16f),
                    1.f / (se2 + 1e-16f), 1.f / (se3 + 1e-16f)};
    unsigned short* row = Agg + (size_t)d * 1024;
    #pragma unroll
    for (int h = 0; h < 4; ++h) {
        __builtin_nontemporal_store(
            pack4(ac[h][0] * inv[h], ac[h][1] * inv[h], ac[h][2] * inv[h], ac[h][3] * inv[h]),
            reinterpret_cast<unsigned long long*>(&row[h * 256 + lane * 4]));
    }
}

// ---------------- fp32 tiled GEMM with fused BN(ReLU) on bf16 A (final N=47 head) ----------------
__global__ __launch_bounds__(256) void gemm64_bn(const unsigned short* __restrict__ A,
                                                 const float* __restrict__ B,
                                                 float* __restrict__ Cmat,
                                                 const float* __restrict__ bias,
                                                 const float* __restrict__ stats,
                                                 const float* __restrict__ gamma,
                                                 const float* __restrict__ beta,
                                                 int M, int N, int K) {
    __shared__ float As[32][68];
    __shared__ float Bs[32][68];
    __shared__ float bnsc[256], bnsh[256];
    const int tid = threadIdx.x;
    {
        int c = tid;
        float invM = 1.f / (float)M;
        float mu = stats[c] * invM;
        float var = stats[256 + c] * invM - mu * mu;
        float sc = rsqrtf(var + kEPS) * gamma[c];
        bnsc[c] = sc;
        bnsh[c] = beta[c] - mu * sc;
    }
    __syncthreads();
    const int tx = tid & 15, ty = tid >> 4;
    const int m0 = blockIdx.y * 64, n0 = blockIdx.x * 64;
    float acc[4][4] = {};

    for (int k0 = 0; k0 < K; k0 += 32) {
        #pragma unroll
        for (int t = 0; t < 2; ++t) {
            int i = tid + t * 256;
            int row = i >> 3;
            int kq = (i & 7) << 2;
            ushort4 u = make_ushort4(0, 0, 0, 0);
            int gr = m0 + row;
            if (gr < M) u = *reinterpret_cast<const ushort4*>(&A[(size_t)gr * K + k0 + kq]);
            #pragma unroll
            for (int j = 0; j < 4; ++j) {
                int k = k0 + kq + j;
                unsigned short uv = (j == 0) ? u.x : (j == 1) ? u.y : (j == 2) ? u.z : u.w;
                float v = b2f(uv) * bnsc[k] + bnsh[k];
                As[kq + j][row] = fmaxf(v, 0.f);
            }
        }
        #pragma unroll
        for (int t = 0; t < 2; ++t) {
            int i = tid + t * 256;
            int kr = i >> 4;
            int cq = (i & 15) << 2;
            #pragma unroll
            for (int j = 0; j < 4; ++j) {
                int gc = n0 + cq + j;
                Bs[kr][cq + j] = (gc < N) ? B[(size_t)(k0 + kr) * N + gc] : 0.f;
            }
        }
        __syncthreads();
        #pragma unroll
        for (int kk = 0; kk < 32; ++kk) {
            float4 a4 = *reinterpret_cast<const float4*>(&As[kk][ty << 2]);
            float4 b4 = *reinterpret_cast<const float4*>(&Bs[kk][tx << 2]);
            float a[4] = {a4.x, a4.y, a4.z, a4.w};
            float b[4] = {b4.x, b4.y, b4.z, b4.w};
            #pragma unroll
            for (int i2 = 0; i2 < 4; ++i2)
                #pragma unroll
                for (int j = 0; j < 4; ++j)
                    acc[i2][j] = fmaf(a[i2], b[j], acc[i2][j]);
        }
        __syncthreads();
    }

    #pragma unroll
    for (int i2 = 0; i2 < 4; ++i2) {
        int row = m0 + (ty << 2) + i2;
        if (row >= M) continue;
        #pragma unroll
        for (int j = 0; j < 4; ++j) {
            int col = n0 + (tx << 2) + j;
            if (col >= N) continue;
            Cmat[(size_t)row * N + col] = acc[i2][j] + bias[col];
        }
    }
}

extern "C" void kernel_launch(void* const* d_in, const int* in_sizes, int n_in,
                              void* d_out, int out_size, void* d_ws, size_t ws_size,
                              hipStream_t stream) {
    (void)in_sizes; (void)n_in; (void)out_size; (void)ws_size;

    const float* x      = (const float*)d_in[0];
    const int*   src1   = (const int*)d_in[1];
    const int*   dst1   = (const int*)d_in[2];
    const int*   src2   = (const int*)d_in[3];
    const int*   dst2   = (const int*)d_in[4];
    const float* W1     = (const float*)d_in[5];
    const float* a_src1 = (const float*)d_in[6];
    const float* a_dst1 = (const float*)d_in[7];
    const float* b1     = (const float*)d_in[8];
    const float* Wsk1   = (const float*)d_in[9];
    const float* bsk1   = (const float*)d_in[10];
    const float* g1     = (const float*)d_in[11];
    const float* be1    = (const float*)d_in[12];
    const float* W2     = (const float*)d_in[13];
    const float* a_src2 = (const float*)d_in[14];
    const float* a_dst2 = (const float*)d_in[15];
    const float* b2     = (const float*)d_in[16];
    const float* Wsk2   = (const float*)d_in[17];
    const float* bsk2   = (const float*)d_in[18];
    const float* g2     = (const float*)d_in[19];
    const float* be2    = (const float*)d_in[20];
    const float* Wm1    = (const float*)d_in[21];
    const float* bm1    = (const float*)d_in[22];
    const float* gm     = (const float*)d_in[23];
    const float* bem    = (const float*)d_in[24];
    const float* Wm2    = (const float*)d_in[25];
    const float* bm2    = (const float*)d_in[26];

    // ---- workspace layout (float units; all chunks 16B-aligned) ----
    float* ws = (float*)d_ws;
    size_t off = 0;
    auto alloc = [&](size_t n) { float* p = ws + off; off += n; return p; };
    unsigned short* xb    = (unsigned short*)alloc((size_t)kN0 * 128 / 2);
    unsigned short* Agg1  = (unsigned short*)alloc((size_t)kN1 * 512 / 2);
    unsigned short* Agg2  = (unsigned short*)alloc((size_t)kN2 * 1024 / 2);
    unsigned short* h1pre = (unsigned short*)alloc((size_t)kN1 * 256 / 2);
    unsigned short* h1b   = (unsigned short*)alloc((size_t)kN1 * 256 / 2);
    unsigned short* h2pre = (unsigned short*)alloc((size_t)kN2 * 256 / 2);
    unsigned short* h2b   = (unsigned short*)alloc((size_t)kN2 * 256 / 2);
    unsigned short* h3pre = (unsigned short*)alloc((size_t)kN2 * 256 / 2);
    unsigned short* Wcat1t = (unsigned short*)alloc(256 * 640 / 2);
    unsigned short* Wcat2t = (unsigned short*)alloc(256 * 1280 / 2);
    unsigned short* Wm1t   = (unsigned short*)alloc(256 * 256 / 2);
    unsigned short* v1t    = (unsigned short*)alloc(16 * 128 / 2);
    unsigned short* v2t    = (unsigned short*)alloc(16 * 256 / 2);
    float4* w1buf = (float4*)alloc((size_t)kE1 * 4);
    float4* w2buf = (float4*)alloc((size_t)kE2 * 4);
    float* als1 = alloc((size_t)kN0 * 4);
    float* ald1 = alloc((size_t)kN1 * 4);
    float* als2 = alloc((size_t)kN1 * 4);
    float* ald2 = alloc((size_t)kN2 * 4);
    float* zreg = alloc(kNZreg);
    float* stats1 = zreg, *stats2 = zreg + 512, *stats3 = zreg + 1024;
    int* cnt1 = (int*)(zreg + 1536);
    int* cur1 = cnt1 + kN1;
    int* cnt2 = cur1 + kN1;
    int* cur2 = cnt2 + kN2;
    int* srcs1  = (int*)alloc(kE1);
    int* offs1  = (int*)alloc(kN1 + 4);
    int* bsum1  = (int*)alloc(128);
    int* srcs2  = (int*)alloc(kE2);
    int* offs2  = (int*)alloc(kN2 + 4);
    int* bsum2  = (int*)alloc(128);

    hipStream_t st = stream;
    const int nb1 = (kN1 + 1023) / 1024;   // 98
    const int nb2 = (kN2 + 1023) / 1024;   // 20

    // ---- init + precomputes (single launch) ----
    prep_all<<<(kNZreg + 563200 + 255) / 256, 256, 0, st>>>(
        W1, a_src1, a_dst1, W2, a_src2, a_dst2, Wsk1, Wsk2, Wm1,
        zreg, v1t, v2t, Wcat1t, Wcat2t, Wm1t);

    // ---- x -> bf16 + layer-1 attention dots (linear R/W, 64 rows/block) || histograms ----
    const int convBlocks = kN0 / 64;                    // 6250
    const int histBlocks = (kE1 + kE2 + 255) / 256;
    conv_als_hist<<<convBlocks + histBlocks, 256, 0, st>>>(
        x, v1t, xb, als1, ald1, dst1, cnt1, dst2, cnt2, convBlocks);

    // ---- CSR scans ----
    scan_block_both<<<nb1 + nb2, 256, 0, st>>>(cnt1, kN1, offs1, bsum1, nb1, cnt2, kN2, offs2, bsum2);
    scan_add_both<<<(kN1 + kN2 + 255) / 256, 256, 0, st>>>(offs1, bsum1, cnt1, kN1, nb1,
                                                           offs2, bsum2, cnt2, kN2, nb2);
    csr_scatter_w<<<(kE1 + 255) / 256, 256, 0, st>>>(dst1, src1, offs1, als1, ald1,
                                                     cur1, srcs1, w1buf, kE1);

    // ================= layer 1 =================
    fused_agg1<<<(kN1 + 3) / 4, 256, 0, st>>>(xb, w1buf, srcs1, offs1, Agg1, kN1);
    gemm_pipe<true, true><<<dim3(2, (kN1 + 127) / 128), 512, 0, st>>>(
        Agg1, 512, xb, 128, Wcat1t, h1pre, b1, bsk1, stats1, kN1, 256, /*rs=*/2, /*kwin=*/256);
    bn_mfma<true><<<1024, 256, 0, st>>>(h1pre, stats1, g1, be1, h1b, v2t, als2, ald2, kN1, kN2);

    // ================= layer 2 =================
    csr_scatter_w<<<(kE2 + 255) / 256, 256, 0, st>>>(dst2, src2, offs2, als2, ald2,
                                                     cur2, srcs2, w2buf, kE2);
    fused_agg2<<<(kN2 + 3) / 4, 256, 0, st>>>(h1b, w2buf, srcs2, offs2, Agg2, kN2);
    gemm_pipe<true, true><<<dim3(2, (kN2 + 127) / 128), 512, 0, st>>>(
        Agg2, 1024, h1b, 256, Wcat2t, h2pre, b2, bsk2, stats2, kN2, 256, /*rs=*/4, /*kwin=*/512);
    bn_mfma<false><<<1024, 256, 0, st>>>(h2pre, stats2, g2, be2, h2b, nullptr, nullptr, nullptr,
                                         kN2, 0);

    // ================= MLP head =================
    gemm_pipe<true, true><<<dim3(2, (kN2 + 127) / 128), 512, 0, st>>>(
        h2b, 256, nullptr, 0, Wm1t, h3pre, bm1, nullptr, stats3, kN2, 256, /*rs=*/0, /*kwin=*/256);
    gemm64_bn<<<dim3(1, (kN2 + 63) / 64), 256, 0, st>>>(
        h3pre, Wm2, (float*)d_out, bm2, stats3, gm, bem, kN2, kOUT, 256);
}